// Round 18
// baseline (1615.671 us; speedup 1.0000x reference)
//
#include <hip/hip_runtime.h>

#define S_   1024
#define ND   30
#define EPS_ 1e-6f

typedef __attribute__((ext_vector_type(8))) short bf16x8;
typedef __attribute__((ext_vector_type(4))) float f32x4;
typedef __attribute__((ext_vector_type(2))) _Float16 h2;
typedef __attribute__((ext_vector_type(8))) _Float16 h8;

// sign of e_a * e_b in Cl(4,1): returns 1 if negative, 0 if positive.
__device__ __forceinline__ int cayley_neg(int a, int b) {
    int par = 0;
    for (int t = a >> 1; t; t >>= 1) par ^= __popc(t & b) & 1;
    par ^= ((a & b) >> 4) & 1;   // metric: generator 4 has e4*e4 = -1
    return par & 1;
}

// exact fp32 -> bf16_hi + bf16_lo split (truncation; v - hi is exact)
__device__ __forceinline__ void split2(float v, ushort& hi, ushort& lo) {
    unsigned bv = __float_as_uint(v);
    hi = (ushort)(bv >> 16);
    float hv = __uint_as_float(bv & 0xffff0000u);
    lo = (ushort)(__float_as_uint(v - hv) >> 16);
}

__device__ __forceinline__ ushort f2h(float v) {
    _Float16 h = (_Float16)v;
    ushort u;
    __builtin_memcpy(&u, &h, 2);
    return u;
}

// cross-lane xor-1 / xor-2 on the VALU (DPP quad_perm) — verified R11/R14/R15/R17.
// NOTE (R12/R13/R16 post-mortems): the mirror/ror/permlane16-swap DPP family
// consistently produced ~0.13 absmax failures (wrong-partner sums in the norm).
// xor4/8/16 MUST stay on __shfl_xor — do not revisit.
__device__ __forceinline__ float dpp_xor1(float v) {
    return __int_as_float(__builtin_amdgcn_update_dpp(
        0, __float_as_int(v), 0xB1 /*quad_perm 1,0,3,2*/, 0xF, 0xF, true));
}
__device__ __forceinline__ float dpp_xor2(float v) {
    return __int_as_float(__builtin_amdgcn_update_dpp(
        0, __float_as_int(v), 0x4E /*quad_perm 2,3,0,1*/, 0xF, 0xF, true));
}

// lgkmcnt-only barrier (never drains vmcnt -> global stores/loads float freely)
#define BAR() asm volatile("s_waitcnt lgkmcnt(0)\n\ts_barrier" ::: "memory")

__launch_bounds__(512, 2)
__global__ void versor_kernel(const float* __restrict__ x,
                              const float* __restrict__ W_in,
                              const float* __restrict__ b_in,
                              const float* __restrict__ w_h,
                              const float* __restrict__ w_x,
                              const float* __restrict__ W_out,
                              const float* __restrict__ b_out,
                              float* __restrict__ out) {
    const int b   = blockIdx.x;
    const int tid = threadIdx.x;
    const int w   = tid >> 6;        // wave 0..7 -> output channels {2w, 2w+1}
    const int ln  = tid & 63;        // lane in wave
    const int g   = ln >> 4;         // k-chunk (A/B frag) / m_mid (C frag) / sel
    const int cl  = ln & 15;         // A row-in-tile, B/C col-in-tile
    const int op  = ln >> 5;         // o' in {0,1}
    const int oo  = 2 * w + op;      // this thread's h channel
    const int kk  = ln & 31;         // this thread's h component
    const int oc  = tid >> 5;        // out-phase channel group (== oo)
    const int lc  = tid & 31;        // out-phase column lane   (== kk)

    // G (=[h | xe]) in MFMA A-fragment layout, bf16 hi/lo, double-buffered:
    // elem = mt*512 + (ich>>3)*128 + (m&15)*8 + (ich&7)
    __shared__ ushort ghi[2][1024];
    __shared__ ushort glo[2][1024];
    __shared__ __align__(16) ushort hf[2][512];    // h in f16, out-phase layout
    __shared__ float red[2][512];
    __shared__ __align__(16) float xt[2][32];      // x-row staging (per-lane
                                                   // vector loads -> vmcnt,
                                                   // NOT s_load/lgkm: keeps
                                                   // HBM latency off the
                                                   // pre-BAR critical path)

    // ---- B fragments (W, step-constant): lane holds B[k=8g+j][nt*16+cl] ----
    bf16x8 bh[2][2], bl[2][2];       // [o'][nt]
    #pragma unroll
    for (int opi = 0; opi < 2; ++opi) {
        #pragma unroll
        for (int nt = 0; nt < 2; ++nt) {
            const int o = 2 * w + opi;
            const int n = nt * 16 + cl;
            #pragma unroll
            for (int j = 0; j < 8; ++j) {
                const int k = g * 8 + j;
                float wv = (k < 16) ? w_h[(o * 16 + k) * 32 + n]
                                    : w_x[(o * 16 + (k - 16)) * 32 + n];
                ushort h_, l_; split2(wv, h_, l_);
                bh[opi][nt][j] = (short)h_;
                bl[opi][nt][j] = (short)l_;
            }
        }
    }

    float win_reg[ND];               // column tid of W_in
    #pragma unroll
    for (int p = 0; p < ND; ++p) win_reg[p] = W_in[p * 512 + tid];
    const float bin_reg = b_in[tid];

    const int pc = (lc < ND) ? lc : 0;
    h2 wout_h2[16];                  // W_out[(oc*32+2j, +2j+1)][pc] as f16 pairs
    #pragma unroll
    for (int j = 0; j < 16; ++j) {
        wout_h2[j][0] = (_Float16)W_out[(oc * 32 + 2 * j) * ND + pc];
        wout_h2[j][1] = (_Float16)W_out[(oc * 32 + 2 * j + 1) * ND + pc];
    }
    const float bout_reg = (tid < ND) ? b_out[tid] : 0.0f;

    // signs as +-1.0f: sgn[mt*8+nt*4+r] = s(m,n), m=mt*16+g*4+r, n=nt*16+cl.
    float sgn[16];
    for (int mt = 0; mt < 2; ++mt)
        for (int nt = 0; nt < 2; ++nt)
            for (int r = 0; r < 4; ++r) {
                int m = mt * 16 + g * 4 + r;
                int n = nt * 16 + cl;
                sgn[mt * 8 + nt * 4 + r] = cayley_neg(m, n) ? -1.0f : 1.0f;
            }

    // fixed LDS element offsets
    const int eh = (kk >> 4) * 512 + (oo >> 3) * 128 + (kk & 15) * 8 + (oo & 7);
    const int ex = (lc >> 4) * 512 + (2 + (oc >> 3)) * 128 + (lc & 15) * 8 + (oc & 7);
    const int ea = g * 128 + cl * 8;     // A-frag read base (+512 for mt=1)

    // redistribute source lane: Z[opi][kt] at lane l holds delta[opi][kt*16+f(l)],
    // f(l) = (l&15) ^ ((g&1)<<2) ^ ((g>>1)<<3); need f(l_src)=cl with g(l_src)=g.
    const int l_src = (g << 4) | (cl ^ ((g & 1) << 2) ^ ((g >> 1) << 3));

    const float* xrow = x   + (size_t)b * S_ * ND;
    float*       orow = out + (size_t)b * S_ * ND;
    const f32x4 z4 = {0.f, 0.f, 0.f, 0.f};

    // ---- prologue: h_0 = 0; xe_0 (direct reads, one-time) -> G[0];
    //      xreg = x row 1 (for xt write at iter 0) ----
    ghi[0][eh] = 0; glo[0][eh] = 0;
    {
        const float* xp = xrow;
        float xe0 = bin_reg, xe1 = 0.f, xe2 = 0.f, xe3 = 0.f;
        #pragma unroll
        for (int q = 0; q < 28; q += 4) {
            xe0 = fmaf(xp[q + 0], win_reg[q + 0], xe0);
            xe1 = fmaf(xp[q + 1], win_reg[q + 1], xe1);
            xe2 = fmaf(xp[q + 2], win_reg[q + 2], xe2);
            xe3 = fmaf(xp[q + 3], win_reg[q + 3], xe3);
        }
        xe0 = fmaf(xp[28], win_reg[28], xe0);
        xe1 = fmaf(xp[29], win_reg[29], xe1);
        float xe = (xe0 + xe1) + (xe2 + xe3);
        ushort xh, xl; split2(xe, xh, xl);
        ghi[0][ex] = xh; glo[0][ex] = xl;
    }
    float xreg = 0.0f;
    if (tid < ND) xreg = xrow[1 * ND + tid];      // row 1, per-lane vector load

    float h_reg = 0.0f, xv_prev = 0.0f;

    // iter s computes h_{s+1} and finishes out[s-1]; iter S_ finishes out[S_-1]
    for (int s = 0; s <= S_; ++s) {
        const int p = s & 1;

        // ---- stage 1 (pre-BAR): x-row pipeline + residual load ----
        float xv_cur = 0.0f;
        if (s < S_) xv_cur = (tid < ND) ? xrow[(size_t)s * ND + tid] : 0.0f;
        if (tid < ND) {
            xt[(s + 1) & 1][tid] = xreg;          // row s+1 (loaded 1 iter ago)
            int nr = (s + 2 < S_) ? s + 2 : S_ - 1;
            xreg = xrow[(size_t)nr * ND + tid];   // issue row s+2 (vmcnt, floats)
        }

        // ---- stage 2: out[s-1] partials from h_s (f16 dot2, 2 ILP chains) ----
        if (s > 0) {
            const ushort* hp = &hf[p][oc * 32];
            float oa0 = 0.0f, oa1 = 0.0f;
            #pragma unroll
            for (int qq = 0; qq < 2; ++qq) {
                h8 hv0 = *(const h8*)(hp + qq * 8);
                h8 hv1 = *(const h8*)(hp + 16 + qq * 8);
                #pragma unroll
                for (int jj = 0; jj < 4; ++jj) {
                    h2 a0 = {hv0[2 * jj], hv0[2 * jj + 1]};
                    h2 a1 = {hv1[2 * jj], hv1[2 * jj + 1]};
                    oa0 = __builtin_amdgcn_fdot2(a0, wout_h2[qq * 4 + jj], oa0, false);
                    oa1 = __builtin_amdgcn_fdot2(a1, wout_h2[8 + qq * 4 + jj], oa1, false);
                }
            }
            red[p][oc * 32 + lc] = oa0 + oa1;
        }

        BAR();   // the ONE barrier: G[p], red[p], xt[(s+1)&1] visible

        // ---- stage 3: finish out[s-1] (global store, never drained) ----
        if (s > 0 && tid < ND) {
            float s0 = 0.f, s1 = 0.f, s2 = 0.f, s3 = 0.f;
            #pragma unroll
            for (int jg = 0; jg < 16; jg += 4) {
                s0 += red[p][(jg + 0) * 32 + tid];
                s1 += red[p][(jg + 1) * 32 + tid];
                s2 += red[p][(jg + 2) * 32 + tid];
                s3 += red[p][(jg + 3) * 32 + tid];
            }
            float ov = xv_prev + bout_reg + ((s0 + s1) + (s2 + s3));
            orow[(size_t)(s - 1) * ND + tid] = ov;
        }

        // ---- stage 3b (post-BAR, hidden under MFMA): xe_{s+1} from xt ----
        // Same values, same accumulation order as R17's stage 1 -> bit-exact.
        // G[p^1] xe slots: read at iter s+1 stage 4 (one BAR later); disjoint
        // from the h slots stage 7 writes below.
        if (s + 1 < S_) {
            const float* xq = &xt[(s + 1) & 1][0];
            float xe0 = bin_reg, xe1 = 0.f, xe2 = 0.f, xe3 = 0.f;
            #pragma unroll
            for (int q = 0; q < 28; q += 4) {
                float4 x4 = *(const float4*)(xq + q);    // uniform broadcast
                xe0 = fmaf(x4.x, win_reg[q + 0], xe0);
                xe1 = fmaf(x4.y, win_reg[q + 1], xe1);
                xe2 = fmaf(x4.z, win_reg[q + 2], xe2);
                xe3 = fmaf(x4.w, win_reg[q + 3], xe3);
            }
            xe0 = fmaf(xq[28], win_reg[28], xe0);
            xe1 = fmaf(xq[29], win_reg[29], xe1);
            float xe = (xe0 + xe1) + (xe2 + xe3);
            ushort xh, xl; split2(xe, xh, xl);
            ghi[p ^ 1][ex] = xh; glo[p ^ 1][ex] = xl;
        }

        if (s < S_) {
            // ---- stage 4: A-fragments + 32 MFMA (FULL 4-term split, R11-exact) ----
            bf16x8 ah0 = *(const bf16x8*)&ghi[p][ea];
            bf16x8 ah1 = *(const bf16x8*)&ghi[p][ea + 512];
            bf16x8 al0 = *(const bf16x8*)&glo[p][ea];
            bf16x8 al1 = *(const bf16x8*)&glo[p][ea + 512];

            f32x4 acc[2][2][2];      // [o'][mt][nt]
            #pragma unroll
            for (int opi = 0; opi < 2; ++opi) {
                #pragma unroll
                for (int nt = 0; nt < 2; ++nt) {
                    f32x4 t = __builtin_amdgcn_mfma_f32_16x16x32_bf16(al0, bl[opi][nt], z4, 0, 0, 0);
                    t = __builtin_amdgcn_mfma_f32_16x16x32_bf16(ah0, bl[opi][nt], t, 0, 0, 0);
                    t = __builtin_amdgcn_mfma_f32_16x16x32_bf16(al0, bh[opi][nt], t, 0, 0, 0);
                    acc[opi][0][nt] = __builtin_amdgcn_mfma_f32_16x16x32_bf16(ah0, bh[opi][nt], t, 0, 0, 0);
                    f32x4 u = __builtin_amdgcn_mfma_f32_16x16x32_bf16(al1, bl[opi][nt], z4, 0, 0, 0);
                    u = __builtin_amdgcn_mfma_f32_16x16x32_bf16(ah1, bl[opi][nt], u, 0, 0, 0);
                    u = __builtin_amdgcn_mfma_f32_16x16x32_bf16(al1, bh[opi][nt], u, 0, 0, 0);
                    acc[opi][1][nt] = __builtin_amdgcn_mfma_f32_16x16x32_bf16(ah1, bh[opi][nt], u, 0, 0, 0);
                }
            }

            // ---- stage 5: sign-fma + XOR-fold (values bit-identical to R17) ----
            float Y[2][2][4];
            #pragma unroll
            for (int opi = 0; opi < 2; ++opi)
                #pragma unroll
                for (int nt = 0; nt < 2; ++nt)
                    #pragma unroll
                    for (int r = 0; r < 4; ++r)
                        Y[opi][nt][r] = fmaf(sgn[nt * 4 + r],
                                             acc[opi][0][nt][r],
                                             sgn[8 + (nt ^ 1) * 4 + r] * acc[opi][1][nt ^ 1][r]);
            float Z[2][2];
            #pragma unroll
            for (int opi = 0; opi < 2; ++opi) {
                #pragma unroll
                for (int kt = 0; kt < 2; ++kt) {
                    float ya0 = Y[opi][kt][0] + dpp_xor1(Y[opi][kt][1]);
                    float ya2 = Y[opi][kt][2] + dpp_xor1(Y[opi][kt][3]);
                    float z = ya0 + dpp_xor2(ya2);
                    z += __shfl_xor(z, 20, 64);
                    z += __shfl_xor(z, 40, 64);
                    Z[opi][kt] = z;
                }
            }
            // select-by-own-g first (3 cndmask), then ONE bpermute from l_src
            float za  = (g & 2) ? Z[1][0] : Z[0][0];
            float zb  = (g & 2) ? Z[1][1] : Z[0][1];
            float sel = (g & 1) ? zb : za;
            const float delta = __shfl(sel, l_src, 64);

            // ---- stage 6: residual + L2 norm (verified tail) ----
            float hc = h_reg + delta;
            float ss = hc * hc;
            ss += dpp_xor1(ss);
            ss += dpp_xor2(ss);
            ss += __shfl_xor(ss, 4, 32);
            ss += __shfl_xor(ss, 8, 32);
            ss += __shfl_xor(ss, 16, 32);
            h_reg = hc / (sqrtf(ss) + EPS_);

            // ---- stage 7: h_{s+1} -> parity p^1 ----
            ushort hh, hl; split2(h_reg, hh, hl);
            ghi[p ^ 1][eh] = hh; glo[p ^ 1][eh] = hl;
            hf[p ^ 1][oo * 32 + kk] = f2h(h_reg);    // slot == tid
        }

        xv_prev = xv_cur;
    }
}

extern "C" void kernel_launch(void* const* d_in, const int* in_sizes, int n_in,
                              void* d_out, int out_size, void* d_ws, size_t ws_size,
                              hipStream_t stream) {
    const float* x     = (const float*)d_in[0];
    const float* W_in  = (const float*)d_in[1];
    const float* b_in  = (const float*)d_in[2];
    const float* w_h   = (const float*)d_in[3];
    const float* w_x   = (const float*)d_in[4];
    const float* W_out = (const float*)d_in[5];
    const float* b_out = (const float*)d_in[6];
    float* outp = (float*)d_out;

    versor_kernel<<<256, 512, 0, stream>>>(x, W_in, b_in, w_h, w_x, W_out, b_out, outp);
}

// Round 19
// 1386.382 us; speedup vs baseline: 1.1654x; 1.1654x over previous
//
#include <hip/hip_runtime.h>

#define S_   1024
#define ND   30
#define EPS_ 1e-6f

typedef __attribute__((ext_vector_type(8))) short bf16x8;
typedef __attribute__((ext_vector_type(4))) float f32x4;
typedef __attribute__((ext_vector_type(2))) _Float16 h2;
typedef __attribute__((ext_vector_type(8))) _Float16 h8;

// sign of e_a * e_b in Cl(4,1): returns 1 if negative, 0 if positive.
__device__ __forceinline__ int cayley_neg(int a, int b) {
    int par = 0;
    for (int t = a >> 1; t; t >>= 1) par ^= __popc(t & b) & 1;
    par ^= ((a & b) >> 4) & 1;   // metric: generator 4 has e4*e4 = -1
    return par & 1;
}

// exact fp32 -> bf16_hi + bf16_lo split (truncation; v - hi is exact)
__device__ __forceinline__ void split2(float v, ushort& hi, ushort& lo) {
    unsigned bv = __float_as_uint(v);
    hi = (ushort)(bv >> 16);
    float hv = __uint_as_float(bv & 0xffff0000u);
    lo = (ushort)(__float_as_uint(v - hv) >> 16);
}

__device__ __forceinline__ ushort f2h(float v) {
    _Float16 h = (_Float16)v;
    ushort u;
    __builtin_memcpy(&u, &h, 2);
    return u;
}

// cross-lane xor-1 / xor-2 on the VALU (DPP quad_perm) — verified R11/R14/R15/R17.
// NOTE (R12/R13/R16 post-mortems): the mirror/ror/permlane16-swap DPP family
// consistently produced ~0.13 absmax failures. xor4/8/16 MUST stay on
// __shfl_xor — do not revisit.
__device__ __forceinline__ float dpp_xor1(float v) {
    return __int_as_float(__builtin_amdgcn_update_dpp(
        0, __float_as_int(v), 0xB1 /*quad_perm 1,0,3,2*/, 0xF, 0xF, true));
}
__device__ __forceinline__ float dpp_xor2(float v) {
    return __int_as_float(__builtin_amdgcn_update_dpp(
        0, __float_as_int(v), 0x4E /*quad_perm 2,3,0,1*/, 0xF, 0xF, true));
}

// lgkmcnt-only barrier (never drains vmcnt -> global stores/loads float freely)
#define BAR() asm volatile("s_waitcnt lgkmcnt(0)\n\ts_barrier" ::: "memory")

__launch_bounds__(512, 2)
__global__ void versor_kernel(const float* __restrict__ x,
                              const float* __restrict__ W_in,
                              const float* __restrict__ b_in,
                              const float* __restrict__ w_h,
                              const float* __restrict__ w_x,
                              const float* __restrict__ W_out,
                              const float* __restrict__ b_out,
                              float* __restrict__ out) {
    const int b   = blockIdx.x;
    const int tid = threadIdx.x;
    const int w   = tid >> 6;        // wave 0..7 -> output channels {2w, 2w+1}
    const int ln  = tid & 63;        // lane in wave
    const int g   = ln >> 4;         // k-chunk (A/B frag) / m_mid (C frag) / sel
    const int cl  = ln & 15;         // A row-in-tile, B/C col-in-tile
    const int op  = ln >> 5;         // o' in {0,1}
    const int oo  = 2 * w + op;      // this thread's h channel
    const int kk  = ln & 31;         // this thread's h component
    const int oc  = tid >> 5;        // out-phase channel group (== oo)
    const int lc  = tid & 31;        // out-phase column lane   (== kk)

    // G (=[h | xe]) in MFMA A-fragment layout, bf16 hi/lo, double-buffered:
    // elem = mt*512 + (ich>>3)*128 + (m&15)*8 + (ich&7)
    __shared__ ushort ghi[2][1024];
    __shared__ ushort glo[2][1024];
    __shared__ __align__(16) ushort hf[2][512];    // h in f16, out-phase layout
    __shared__ float red[2][512];

    // ---- B fragments (W, step-constant): lane holds B[k=8g+j][nt*16+cl] ----
    bf16x8 bh[2][2], bl[2][2];       // [o'][nt]
    #pragma unroll
    for (int opi = 0; opi < 2; ++opi) {
        #pragma unroll
        for (int nt = 0; nt < 2; ++nt) {
            const int o = 2 * w + opi;
            const int n = nt * 16 + cl;
            #pragma unroll
            for (int j = 0; j < 8; ++j) {
                const int k = g * 8 + j;
                float wv = (k < 16) ? w_h[(o * 16 + k) * 32 + n]
                                    : w_x[(o * 16 + (k - 16)) * 32 + n];
                ushort h_, l_; split2(wv, h_, l_);
                bh[opi][nt][j] = (short)h_;
                bl[opi][nt][j] = (short)l_;
            }
        }
    }

    float win_reg[ND];               // column tid of W_in
    #pragma unroll
    for (int p = 0; p < ND; ++p) win_reg[p] = W_in[p * 512 + tid];
    const float bin_reg = b_in[tid];

    const int pc = (lc < ND) ? lc : 0;
    h2 wout_h2[16];                  // W_out[(oc*32+2j, +2j+1)][pc] as f16 pairs
    #pragma unroll
    for (int j = 0; j < 16; ++j) {
        wout_h2[j][0] = (_Float16)W_out[(oc * 32 + 2 * j) * ND + pc];
        wout_h2[j][1] = (_Float16)W_out[(oc * 32 + 2 * j + 1) * ND + pc];
    }
    const float bout_reg = (tid < ND) ? b_out[tid] : 0.0f;

    // signs as +-1.0f: sgn[mt*8+nt*4+r] = s(m,n), m=mt*16+g*4+r, n=nt*16+cl.
    float sgn[16];
    for (int mt = 0; mt < 2; ++mt)
        for (int nt = 0; nt < 2; ++nt)
            for (int r = 0; r < 4; ++r) {
                int m = mt * 16 + g * 4 + r;
                int n = nt * 16 + cl;
                sgn[mt * 8 + nt * 4 + r] = cayley_neg(m, n) ? -1.0f : 1.0f;
            }

    // fixed LDS element offsets
    const int eh = (kk >> 4) * 512 + (oo >> 3) * 128 + (kk & 15) * 8 + (oo & 7);
    const int ex = (lc >> 4) * 512 + (2 + (oc >> 3)) * 128 + (lc & 15) * 8 + (oc & 7);
    const int ea = g * 128 + cl * 8;     // A-frag read base (+512 for mt=1)

    // redistribute source lane: Z[opi][kt] at lane l holds delta[opi][kt*16+f(l)],
    // f(l) = (l&15) ^ ((g&1)<<2) ^ ((g>>1)<<3); need f(l_src)=cl with g(l_src)=g.
    const int l_src = (g << 4) | (cl ^ ((g & 1) << 2) ^ ((g >> 1) << 3));

    ghi[0][eh] = 0; glo[0][eh] = 0;      // h_0 = 0 (parity-0 h slots)

    float h_reg = 0.0f, xv_prev = 0.0f;
    const float* xrow = x   + (size_t)b * S_ * ND;
    float*       orow = out + (size_t)b * S_ * ND;
    const f32x4 z4 = {0.f, 0.f, 0.f, 0.f};

    // iter s computes h_{s+1} and finishes out[s-1]; iter S_ finishes out[S_-1]
    for (int s = 0; s <= S_; ++s) {
        const int p = s & 1;

        // ---- stage 1: xe (uniform x loads), 4-way ILP, -> G[p] ----
        float xv_cur = 0.0f;
        if (s < S_) {
            const float* xp = xrow + s * ND;
            xv_cur = (tid < ND) ? xp[tid] : 0.0f;
            float xe0 = bin_reg, xe1 = 0.f, xe2 = 0.f, xe3 = 0.f;
            #pragma unroll
            for (int q = 0; q < 28; q += 4) {
                xe0 = fmaf(xp[q + 0], win_reg[q + 0], xe0);
                xe1 = fmaf(xp[q + 1], win_reg[q + 1], xe1);
                xe2 = fmaf(xp[q + 2], win_reg[q + 2], xe2);
                xe3 = fmaf(xp[q + 3], win_reg[q + 3], xe3);
            }
            xe0 = fmaf(xp[28], win_reg[28], xe0);
            xe1 = fmaf(xp[29], win_reg[29], xe1);
            float xe = (xe0 + xe1) + (xe2 + xe3);
            ushort xh, xl; split2(xe, xh, xl);
            ghi[p][ex] = xh; glo[p][ex] = xl;
        }

        // ---- stage 2: out[s-1] partials from h_s (f16 dot2, 2 ILP chains) ----
        if (s > 0) {
            const ushort* hp = &hf[p][oc * 32];
            float oa0 = 0.0f, oa1 = 0.0f;
            #pragma unroll
            for (int qq = 0; qq < 2; ++qq) {
                h8 hv0 = *(const h8*)(hp + qq * 8);
                h8 hv1 = *(const h8*)(hp + 16 + qq * 8);
                #pragma unroll
                for (int jj = 0; jj < 4; ++jj) {
                    h2 a0 = {hv0[2 * jj], hv0[2 * jj + 1]};
                    h2 a1 = {hv1[2 * jj], hv1[2 * jj + 1]};
                    oa0 = __builtin_amdgcn_fdot2(a0, wout_h2[qq * 4 + jj], oa0, false);
                    oa1 = __builtin_amdgcn_fdot2(a1, wout_h2[8 + qq * 4 + jj], oa1, false);
                }
            }
            red[p][oc * 32 + lc] = oa0 + oa1;
        }

        BAR();   // the ONE barrier: G[p] (h from s-1 tail, xe), red[p] visible

        // ---- stage 3: finish out[s-1] (global store, never drained) ----
        if (s > 0 && tid < ND) {
            float s0 = 0.f, s1 = 0.f, s2 = 0.f, s3 = 0.f;
            #pragma unroll
            for (int jg = 0; jg < 16; jg += 4) {
                s0 += red[p][(jg + 0) * 32 + tid];
                s1 += red[p][(jg + 1) * 32 + tid];
                s2 += red[p][(jg + 2) * 32 + tid];
                s3 += red[p][(jg + 3) * 32 + tid];
            }
            float ov = xv_prev + bout_reg + ((s0 + s1) + (s2 + s3));
            orow[(size_t)(s - 1) * ND + tid] = ov;
        }

        if (s < S_) {
            // ---- stage 4: A-fragments + 32 MFMA (FULL 4-term split, R11-exact) ----
            bf16x8 ah0 = *(const bf16x8*)&ghi[p][ea];
            bf16x8 ah1 = *(const bf16x8*)&ghi[p][ea + 512];
            bf16x8 al0 = *(const bf16x8*)&glo[p][ea];
            bf16x8 al1 = *(const bf16x8*)&glo[p][ea + 512];

            f32x4 acc[2][2][2];      // [o'][mt][nt]
            #pragma unroll
            for (int opi = 0; opi < 2; ++opi) {
                #pragma unroll
                for (int nt = 0; nt < 2; ++nt) {
                    f32x4 t = __builtin_amdgcn_mfma_f32_16x16x32_bf16(al0, bl[opi][nt], z4, 0, 0, 0);
                    t = __builtin_amdgcn_mfma_f32_16x16x32_bf16(ah0, bl[opi][nt], t, 0, 0, 0);
                    t = __builtin_amdgcn_mfma_f32_16x16x32_bf16(al0, bh[opi][nt], t, 0, 0, 0);
                    acc[opi][0][nt] = __builtin_amdgcn_mfma_f32_16x16x32_bf16(ah0, bh[opi][nt], t, 0, 0, 0);
                    f32x4 u = __builtin_amdgcn_mfma_f32_16x16x32_bf16(al1, bl[opi][nt], z4, 0, 0, 0);
                    u = __builtin_amdgcn_mfma_f32_16x16x32_bf16(ah1, bl[opi][nt], u, 0, 0, 0);
                    u = __builtin_amdgcn_mfma_f32_16x16x32_bf16(al1, bh[opi][nt], u, 0, 0, 0);
                    acc[opi][1][nt] = __builtin_amdgcn_mfma_f32_16x16x32_bf16(ah1, bh[opi][nt], u, 0, 0, 0);
                }
            }

            // ---- stage 5: sign-fma + in-lane dpp folds -> z0[opi][kt] ----
            float Y[2][2][4];
            #pragma unroll
            for (int opi = 0; opi < 2; ++opi)
                #pragma unroll
                for (int nt = 0; nt < 2; ++nt)
                    #pragma unroll
                    for (int r = 0; r < 4; ++r)
                        Y[opi][nt][r] = fmaf(sgn[nt * 4 + r],
                                             acc[opi][0][nt][r],
                                             sgn[8 + (nt ^ 1) * 4 + r] * acc[opi][1][nt ^ 1][r]);
            float z0[2][2];
            #pragma unroll
            for (int opi = 0; opi < 2; ++opi) {
                #pragma unroll
                for (int kt = 0; kt < 2; ++kt) {
                    float ya0 = Y[opi][kt][0] + dpp_xor1(Y[opi][kt][1]);
                    float ya2 = Y[opi][kt][2] + dpp_xor1(Y[opi][kt][3]);
                    z0[opi][kt] = ya0 + dpp_xor2(ya2);
                }
            }

            // ---- orbit fold, 3 parallel shuffles (was 8 serial-2-deep).
            // Lane target: opX = g>>1, ktX = g&1. Orbit {l, l^20, l^40, l^60};
            // masks 20/40 flip g-bits 4/5, so the partner's contribution in
            // ITS OWN indices is b/c/d below. Association (A+B)+(C+D) matches
            // the old z+=xor20; z+=xor40 chain bit-exactly (C+D is the
            // partner-lane's A+B order).
            float p0 = (g & 2) ? z0[1][0] : z0[0][0];
            float p1 = (g & 2) ? z0[1][1] : z0[0][1];
            float q0 = (g & 2) ? z0[0][0] : z0[1][0];
            float q1 = (g & 2) ? z0[0][1] : z0[1][1];
            float a_ = (g & 1) ? p1 : p0;     // z0[opX][ktX]
            float b_ = (g & 1) ? p0 : p1;     // z0[opX][ktX^1]
            float c_ = (g & 1) ? q1 : q0;     // z0[opX^1][ktX]
            float d_ = (g & 1) ? q0 : q1;     // z0[opX^1][ktX^1]
            float t1 = a_ + __shfl_xor(b_, 20, 64);
            float t2 = __shfl_xor(c_, 40, 64) + __shfl_xor(d_, 60, 64);
            float F  = t1 + t2;               // = Z[g>>1][g&1] at this lane

            // redistribute (unchanged): delta = F at lane l_src
            const float delta = __shfl(F, l_src, 64);

            // ---- stage 6: residual + L2 norm (verified tail) ----
            float hc = h_reg + delta;
            float ss = hc * hc;
            ss += dpp_xor1(ss);
            ss += dpp_xor2(ss);
            ss += __shfl_xor(ss, 4, 32);
            ss += __shfl_xor(ss, 8, 32);
            ss += __shfl_xor(ss, 16, 32);
            h_reg = hc / (sqrtf(ss) + EPS_);

            // ---- stage 7: h_{s+1} -> parity p^1 ----
            ushort hh, hl; split2(h_reg, hh, hl);
            ghi[p ^ 1][eh] = hh; glo[p ^ 1][eh] = hl;
            hf[p ^ 1][oo * 32 + kk] = f2h(h_reg);    // slot == tid
        }

        xv_prev = xv_cur;
    }
}

extern "C" void kernel_launch(void* const* d_in, const int* in_sizes, int n_in,
                              void* d_out, int out_size, void* d_ws, size_t ws_size,
                              hipStream_t stream) {
    const float* x     = (const float*)d_in[0];
    const float* W_in  = (const float*)d_in[1];
    const float* b_in  = (const float*)d_in[2];
    const float* w_h   = (const float*)d_in[3];
    const float* w_x   = (const float*)d_in[4];
    const float* W_out = (const float*)d_in[5];
    const float* b_out = (const float*)d_in[6];
    float* outp = (float*)d_out;

    versor_kernel<<<256, 512, 0, stream>>>(x, W_in, b_in, w_h, w_x, W_out, b_out, outp);
}

// Round 20
// 1258.523 us; speedup vs baseline: 1.2838x; 1.1016x over previous
//
#include <hip/hip_runtime.h>

#define S_   1024
#define ND   30
#define EPS_ 1e-6f

typedef __attribute__((ext_vector_type(8))) short bf16x8;
typedef __attribute__((ext_vector_type(4))) float f32x4;
typedef __attribute__((ext_vector_type(2))) _Float16 h2;
typedef __attribute__((ext_vector_type(8))) _Float16 h8;

// sign of e_a * e_b in Cl(4,1): returns 1 if negative, 0 if positive.
__device__ __forceinline__ int cayley_neg(int a, int b) {
    int par = 0;
    for (int t = a >> 1; t; t >>= 1) par ^= __popc(t & b) & 1;
    par ^= ((a & b) >> 4) & 1;   // metric: generator 4 has e4*e4 = -1
    return par & 1;
}

// exact fp32 -> bf16_hi + bf16_lo split (truncation; v - hi is exact)
__device__ __forceinline__ void split2(float v, ushort& hi, ushort& lo) {
    unsigned bv = __float_as_uint(v);
    hi = (ushort)(bv >> 16);
    float hv = __uint_as_float(bv & 0xffff0000u);
    lo = (ushort)(__float_as_uint(v - hv) >> 16);
}

__device__ __forceinline__ ushort f2h(float v) {
    _Float16 h = (_Float16)v;
    ushort u;
    __builtin_memcpy(&u, &h, 2);
    return u;
}

// cross-lane xor-1 / xor-2 on the VALU (DPP quad_perm) — verified R11..R19.
// NOTE (R12/R13/R16 post-mortems): the mirror/ror/permlane16-swap DPP family
// consistently produced ~0.13 absmax failures. xor4/8/16 MUST stay on
// __shfl_xor — do not revisit.
__device__ __forceinline__ float dpp_xor1(float v) {
    return __int_as_float(__builtin_amdgcn_update_dpp(
        0, __float_as_int(v), 0xB1 /*quad_perm 1,0,3,2*/, 0xF, 0xF, true));
}
__device__ __forceinline__ float dpp_xor2(float v) {
    return __int_as_float(__builtin_amdgcn_update_dpp(
        0, __float_as_int(v), 0x4E /*quad_perm 2,3,0,1*/, 0xF, 0xF, true));
}

// lgkmcnt-only barrier (never drains vmcnt -> global stores/loads float freely)
#define BAR() asm volatile("s_waitcnt lgkmcnt(0)\n\ts_barrier" ::: "memory")

__launch_bounds__(512, 2)
__global__ void versor_kernel(const float* __restrict__ x,
                              const float* __restrict__ W_in,
                              const float* __restrict__ b_in,
                              const float* __restrict__ w_h,
                              const float* __restrict__ w_x,
                              const float* __restrict__ W_out,
                              const float* __restrict__ b_out,
                              float* __restrict__ out) {
    const int b   = blockIdx.x;
    const int tid = threadIdx.x;
    const int w   = tid >> 6;        // wave 0..7 -> output channels {2w, 2w+1}
    const int ln  = tid & 63;        // lane in wave
    const int g   = ln >> 4;         // k-chunk (A/B frag) / m_mid (C frag) / sel
    const int cl  = ln & 15;         // A row-in-tile, B/C col-in-tile
    const int op  = ln >> 5;         // o' in {0,1}
    const int oo  = 2 * w + op;      // this thread's h channel
    const int kk  = ln & 31;         // this thread's h component
    const int oc  = tid >> 5;        // out-phase channel group (== oo)
    const int lc  = tid & 31;        // out-phase column lane   (== kk)

    // G (=[h | xe]) in MFMA A-fragment layout, bf16 hi/lo, double-buffered:
    // elem = mt*512 + (ich>>3)*128 + (m&15)*8 + (ich&7)
    __shared__ ushort ghi[2][1024];
    __shared__ ushort glo[2][1024];
    __shared__ __align__(16) ushort hf[2][512];    // h in f16, out-phase layout
    __shared__ float red[2][512];

    // ---- B fragments (W, step-constant): lane holds B[k=8g+j][nt*16+cl] ----
    bf16x8 bh[2][2], bl[2][2];       // [o'][nt]
    #pragma unroll
    for (int opi = 0; opi < 2; ++opi) {
        #pragma unroll
        for (int nt = 0; nt < 2; ++nt) {
            const int o = 2 * w + opi;
            const int n = nt * 16 + cl;
            #pragma unroll
            for (int j = 0; j < 8; ++j) {
                const int k = g * 8 + j;
                float wv = (k < 16) ? w_h[(o * 16 + k) * 32 + n]
                                    : w_x[(o * 16 + (k - 16)) * 32 + n];
                ushort h_, l_; split2(wv, h_, l_);
                bh[opi][nt][j] = (short)h_;
                bl[opi][nt][j] = (short)l_;
            }
        }
    }

    float win_reg[ND];               // column tid of W_in
    #pragma unroll
    for (int p = 0; p < ND; ++p) win_reg[p] = W_in[p * 512 + tid];
    const float bin_reg = b_in[tid];

    const int pc = (lc < ND) ? lc : 0;
    h2 wout_h2[16];                  // W_out[(oc*32+2j, +2j+1)][pc] as f16 pairs
    #pragma unroll
    for (int j = 0; j < 16; ++j) {
        wout_h2[j][0] = (_Float16)W_out[(oc * 32 + 2 * j) * ND + pc];
        wout_h2[j][1] = (_Float16)W_out[(oc * 32 + 2 * j + 1) * ND + pc];
    }
    const float bout_reg = (tid < ND) ? b_out[tid] : 0.0f;

    // signs as +-1.0f: sgn[mt*8+nt*4+r] = s(m,n), m=mt*16+g*4+r, n=nt*16+cl.
    float sgn[16];
    for (int mt = 0; mt < 2; ++mt)
        for (int nt = 0; nt < 2; ++nt)
            for (int r = 0; r < 4; ++r) {
                int m = mt * 16 + g * 4 + r;
                int n = nt * 16 + cl;
                sgn[mt * 8 + nt * 4 + r] = cayley_neg(m, n) ? -1.0f : 1.0f;
            }

    // fixed LDS element offsets
    const int eh = (kk >> 4) * 512 + (oo >> 3) * 128 + (kk & 15) * 8 + (oo & 7);
    const int ex = (lc >> 4) * 512 + (2 + (oc >> 3)) * 128 + (lc & 15) * 8 + (oc & 7);
    const int ea = g * 128 + cl * 8;     // A-frag read base (+512 for mt=1)

    // redistribute source lane: F at lane l holds delta[opX=g>>1][ (g&1)*16+f(l) ],
    // f(l) = (l&15) ^ ((g&1)<<2) ^ ((g>>1)<<3); need f(l_src)=cl with g(l_src)=g.
    const int l_src = (g << 4) | (cl ^ ((g & 1) << 2) ^ ((g >> 1) << 3));

    ghi[0][eh] = 0; glo[0][eh] = 0;      // h_0 = 0 (parity-0 h slots)

    float h_reg = 0.0f, xv_prev = 0.0f;
    const float* xrow = x   + (size_t)b * S_ * ND;
    float*       orow = out + (size_t)b * S_ * ND;
    const f32x4 z4 = {0.f, 0.f, 0.f, 0.f};

    // iter s computes h_{s+1} and finishes out[s-1]; iter S_ finishes out[S_-1]
    for (int s = 0; s <= S_; ++s) {
        const int p = s & 1;

        // ---- stage 1: xe (uniform x loads), 4-way ILP, -> G[p] ----
        float xv_cur = 0.0f;
        if (s < S_) {
            const float* xp = xrow + s * ND;
            xv_cur = (tid < ND) ? xp[tid] : 0.0f;
            float xe0 = bin_reg, xe1 = 0.f, xe2 = 0.f, xe3 = 0.f;
            #pragma unroll
            for (int q = 0; q < 28; q += 4) {
                xe0 = fmaf(xp[q + 0], win_reg[q + 0], xe0);
                xe1 = fmaf(xp[q + 1], win_reg[q + 1], xe1);
                xe2 = fmaf(xp[q + 2], win_reg[q + 2], xe2);
                xe3 = fmaf(xp[q + 3], win_reg[q + 3], xe3);
            }
            xe0 = fmaf(xp[28], win_reg[28], xe0);
            xe1 = fmaf(xp[29], win_reg[29], xe1);
            float xe = (xe0 + xe1) + (xe2 + xe3);
            ushort xh, xl; split2(xe, xh, xl);
            ghi[p][ex] = xh; glo[p][ex] = xl;
        }

        // ---- stage 2: out[s-1] partials from h_s (f16 dot2, 2 ILP chains) ----
        if (s > 0) {
            const ushort* hp = &hf[p][oc * 32];
            float oa0 = 0.0f, oa1 = 0.0f;
            #pragma unroll
            for (int qq = 0; qq < 2; ++qq) {
                h8 hv0 = *(const h8*)(hp + qq * 8);
                h8 hv1 = *(const h8*)(hp + 16 + qq * 8);
                #pragma unroll
                for (int jj = 0; jj < 4; ++jj) {
                    h2 a0 = {hv0[2 * jj], hv0[2 * jj + 1]};
                    h2 a1 = {hv1[2 * jj], hv1[2 * jj + 1]};
                    oa0 = __builtin_amdgcn_fdot2(a0, wout_h2[qq * 4 + jj], oa0, false);
                    oa1 = __builtin_amdgcn_fdot2(a1, wout_h2[8 + qq * 4 + jj], oa1, false);
                }
            }
            red[p][oc * 32 + lc] = oa0 + oa1;
        }

        BAR();   // the ONE barrier: G[p] (h from s-1 tail, xe), red[p] visible

        // ---- stage 3: finish out[s-1] (global store, never drained) ----
        if (s > 0 && tid < ND) {
            float s0 = 0.f, s1 = 0.f, s2 = 0.f, s3 = 0.f;
            #pragma unroll
            for (int jg = 0; jg < 16; jg += 4) {
                s0 += red[p][(jg + 0) * 32 + tid];
                s1 += red[p][(jg + 1) * 32 + tid];
                s2 += red[p][(jg + 2) * 32 + tid];
                s3 += red[p][(jg + 3) * 32 + tid];
            }
            float ov = xv_prev + bout_reg + ((s0 + s1) + (s2 + s3));
            orow[(size_t)(s - 1) * ND + tid] = ov;
        }

        if (s < S_) {
            // ---- stage 4: A-fragments + 24 MFMA (3-term split: hh+hl+lh).
            // R12-vs-R13 evidence: dropping al*bl changed absmax by only 0.001
            // under identical (bad-norm) conditions -> numerically safe; the
            // ~0.13 failures were entirely the norm tail. -25% matrix-pipe
            // time, dependent chain 4 -> 3 deep. ----
            bf16x8 ah0 = *(const bf16x8*)&ghi[p][ea];
            bf16x8 ah1 = *(const bf16x8*)&ghi[p][ea + 512];
            bf16x8 al0 = *(const bf16x8*)&glo[p][ea];
            bf16x8 al1 = *(const bf16x8*)&glo[p][ea + 512];

            f32x4 acc[2][2][2];      // [o'][mt][nt]
            #pragma unroll
            for (int opi = 0; opi < 2; ++opi) {
                #pragma unroll
                for (int nt = 0; nt < 2; ++nt) {
                    f32x4 t = __builtin_amdgcn_mfma_f32_16x16x32_bf16(ah0, bl[opi][nt], z4, 0, 0, 0);
                    t = __builtin_amdgcn_mfma_f32_16x16x32_bf16(al0, bh[opi][nt], t, 0, 0, 0);
                    acc[opi][0][nt] = __builtin_amdgcn_mfma_f32_16x16x32_bf16(ah0, bh[opi][nt], t, 0, 0, 0);
                    f32x4 u = __builtin_amdgcn_mfma_f32_16x16x32_bf16(ah1, bl[opi][nt], z4, 0, 0, 0);
                    u = __builtin_amdgcn_mfma_f32_16x16x32_bf16(al1, bh[opi][nt], u, 0, 0, 0);
                    acc[opi][1][nt] = __builtin_amdgcn_mfma_f32_16x16x32_bf16(ah1, bh[opi][nt], u, 0, 0, 0);
                }
            }

            // ---- stage 5: sign-fma + in-lane dpp folds -> z0[opi][kt] ----
            float Y[2][2][4];
            #pragma unroll
            for (int opi = 0; opi < 2; ++opi)
                #pragma unroll
                for (int nt = 0; nt < 2; ++nt)
                    #pragma unroll
                    for (int r = 0; r < 4; ++r)
                        Y[opi][nt][r] = fmaf(sgn[nt * 4 + r],
                                             acc[opi][0][nt][r],
                                             sgn[8 + (nt ^ 1) * 4 + r] * acc[opi][1][nt ^ 1][r]);
            float z0[2][2];
            #pragma unroll
            for (int opi = 0; opi < 2; ++opi) {
                #pragma unroll
                for (int kt = 0; kt < 2; ++kt) {
                    float ya0 = Y[opi][kt][0] + dpp_xor1(Y[opi][kt][1]);
                    float ya2 = Y[opi][kt][2] + dpp_xor1(Y[opi][kt][3]);
                    z0[opi][kt] = ya0 + dpp_xor2(ya2);
                }
            }

            // ---- orbit fold, 3 parallel shuffles (R19-verified) ----
            float p0 = (g & 2) ? z0[1][0] : z0[0][0];
            float p1 = (g & 2) ? z0[1][1] : z0[0][1];
            float q0 = (g & 2) ? z0[0][0] : z0[1][0];
            float q1 = (g & 2) ? z0[0][1] : z0[1][1];
            float a_ = (g & 1) ? p1 : p0;     // z0[opX][ktX]
            float b_ = (g & 1) ? p0 : p1;     // z0[opX][ktX^1]
            float c_ = (g & 1) ? q1 : q0;     // z0[opX^1][ktX]
            float d_ = (g & 1) ? q0 : q1;     // z0[opX^1][ktX^1]
            float t1 = a_ + __shfl_xor(b_, 20, 64);
            float t2 = __shfl_xor(c_, 40, 64) + __shfl_xor(d_, 60, 64);
            float F  = t1 + t2;               // = Z[g>>1][g&1] at this lane

            // redistribute: delta = F at lane l_src
            const float delta = __shfl(F, l_src, 64);

            // ---- stage 6: residual + L2 norm (verified tail) ----
            float hc = h_reg + delta;
            float ss = hc * hc;
            ss += dpp_xor1(ss);
            ss += dpp_xor2(ss);
            ss += __shfl_xor(ss, 4, 32);
            ss += __shfl_xor(ss, 8, 32);
            ss += __shfl_xor(ss, 16, 32);
            h_reg = hc / (sqrtf(ss) + EPS_);

            // ---- stage 7: h_{s+1} -> parity p^1 ----
            ushort hh, hl; split2(h_reg, hh, hl);
            ghi[p ^ 1][eh] = hh; glo[p ^ 1][eh] = hl;
            hf[p ^ 1][oo * 32 + kk] = f2h(h_reg);    // slot == tid
        }

        xv_prev = xv_cur;
    }
}

extern "C" void kernel_launch(void* const* d_in, const int* in_sizes, int n_in,
                              void* d_out, int out_size, void* d_ws, size_t ws_size,
                              hipStream_t stream) {
    const float* x     = (const float*)d_in[0];
    const float* W_in  = (const float*)d_in[1];
    const float* b_in  = (const float*)d_in[2];
    const float* w_h   = (const float*)d_in[3];
    const float* w_x   = (const float*)d_in[4];
    const float* W_out = (const float*)d_in[5];
    const float* b_out = (const float*)d_in[6];
    float* outp = (float*)d_out;

    versor_kernel<<<256, 512, 0, stream>>>(x, W_in, b_in, w_h, w_x, W_out, b_out, outp);
}

// Round 21
// 1158.627 us; speedup vs baseline: 1.3945x; 1.0862x over previous
//
#include <hip/hip_runtime.h>

#define S_   1024
#define ND   30
#define EPS_ 1e-6f

typedef __attribute__((ext_vector_type(8))) short bf16x8;
typedef __attribute__((ext_vector_type(4))) float f32x4;
typedef __attribute__((ext_vector_type(2))) _Float16 h2;
typedef __attribute__((ext_vector_type(8))) _Float16 h8;

// sign of e_a * e_b in Cl(4,1): returns 1 if negative, 0 if positive.
__device__ __forceinline__ int cayley_neg(int a, int b) {
    int par = 0;
    for (int t = a >> 1; t; t >>= 1) par ^= __popc(t & b) & 1;
    par ^= ((a & b) >> 4) & 1;   // metric: generator 4 has e4*e4 = -1
    return par & 1;
}

// exact fp32 -> bf16_hi + bf16_lo split (truncation; v - hi is exact)
__device__ __forceinline__ void split2(float v, ushort& hi, ushort& lo) {
    unsigned bv = __float_as_uint(v);
    hi = (ushort)(bv >> 16);
    float hv = __uint_as_float(bv & 0xffff0000u);
    lo = (ushort)(__float_as_uint(v - hv) >> 16);
}

__device__ __forceinline__ ushort f2h(float v) {
    _Float16 h = (_Float16)v;
    ushort u;
    __builtin_memcpy(&u, &h, 2);
    return u;
}

// cross-lane xor-1 / xor-2 on the VALU (DPP quad_perm) — verified R11..R20.
// NOTE (R12/R13/R16 post-mortems): the mirror/ror/permlane16-swap DPP family
// consistently produced ~0.13 absmax failures. xor4/8/16 MUST stay on
// __shfl_xor — do not revisit.
__device__ __forceinline__ float dpp_xor1(float v) {
    return __int_as_float(__builtin_amdgcn_update_dpp(
        0, __float_as_int(v), 0xB1 /*quad_perm 1,0,3,2*/, 0xF, 0xF, true));
}
__device__ __forceinline__ float dpp_xor2(float v) {
    return __int_as_float(__builtin_amdgcn_update_dpp(
        0, __float_as_int(v), 0x4E /*quad_perm 2,3,0,1*/, 0xF, 0xF, true));
}

// lgkmcnt-only barrier (never drains vmcnt -> global stores/loads float freely)
#define BAR() asm volatile("s_waitcnt lgkmcnt(0)\n\ts_barrier" ::: "memory")

__launch_bounds__(512, 2)
__global__ void versor_kernel(const float* __restrict__ x,
                              const float* __restrict__ W_in,
                              const float* __restrict__ b_in,
                              const float* __restrict__ w_h,
                              const float* __restrict__ w_x,
                              const float* __restrict__ W_out,
                              const float* __restrict__ b_out,
                              float* __restrict__ out) {
    const int b   = blockIdx.x;
    const int tid = threadIdx.x;
    const int w   = tid >> 6;        // wave 0..7 -> output channels {2w, 2w+1}
    const int ln  = tid & 63;        // lane in wave
    const int g   = ln >> 4;         // k-chunk (A/B frag) / m_mid (C frag) / sel
    const int cl  = ln & 15;         // A row-in-tile, B/C col-in-tile
    const int oo  = 2 * w + (g >> 1);// this thread's h channel (== old oo)
    // Component ownership remap (R21): after the orbit fold, lane l ALREADY
    // holds F = delta[g>>1][(g&1)*16 + f(l)], f(l)=cl^((g&1)<<2)^((g>>1)<<3)
    // (R19/R20 hardware-verified mapping). Own THAT component -> the final
    // redistribute bpermute disappears. Bijective within each 32-lane half;
    // channel unchanged; only per-thread constants change.
    const int kkp = ((g & 1) << 4) | (cl ^ ((g & 1) << 2) ^ ((g >> 1) << 3));
    const int oc  = tid >> 5;        // out-phase channel group (== oo)
    const int lc  = tid & 31;        // out-phase column lane

    // G (=[h | xe]) in MFMA A-fragment layout, bf16 hi/lo, double-buffered:
    // elem = mt*512 + (ich>>3)*128 + (m&15)*8 + (ich&7)
    __shared__ ushort ghi[2][1024];
    __shared__ ushort glo[2][1024];
    __shared__ __align__(16) ushort hf[2][512];    // h in f16, out-phase layout
    __shared__ float red[2][512];

    // ---- B fragments (W, step-constant): lane holds B[k=8g+j][nt*16+cl] ----
    bf16x8 bh[2][2], bl[2][2];       // [o'][nt]
    #pragma unroll
    for (int opi = 0; opi < 2; ++opi) {
        #pragma unroll
        for (int nt = 0; nt < 2; ++nt) {
            const int o = 2 * w + opi;
            const int n = nt * 16 + cl;
            #pragma unroll
            for (int j = 0; j < 8; ++j) {
                const int k = g * 8 + j;
                float wv = (k < 16) ? w_h[(o * 16 + k) * 32 + n]
                                    : w_x[(o * 16 + (k - 16)) * 32 + n];
                ushort h_, l_; split2(wv, h_, l_);
                bh[opi][nt][j] = (short)h_;
                bl[opi][nt][j] = (short)l_;
            }
        }
    }

    float win_reg[ND];               // column tid of W_in
    #pragma unroll
    for (int p = 0; p < ND; ++p) win_reg[p] = W_in[p * 512 + tid];
    const float bin_reg = b_in[tid];

    const int pc = (lc < ND) ? lc : 0;
    h2 wout_h2[16];                  // W_out[(oc*32+2j, +2j+1)][pc] as f16 pairs
    #pragma unroll
    for (int j = 0; j < 16; ++j) {
        wout_h2[j][0] = (_Float16)W_out[(oc * 32 + 2 * j) * ND + pc];
        wout_h2[j][1] = (_Float16)W_out[(oc * 32 + 2 * j + 1) * ND + pc];
    }
    const float bout_reg = (tid < ND) ? b_out[tid] : 0.0f;

    // signs as +-1.0f: sgn[mt*8+nt*4+r] = s(m,n), m=mt*16+g*4+r, n=nt*16+cl.
    float sgn[16];
    for (int mt = 0; mt < 2; ++mt)
        for (int nt = 0; nt < 2; ++nt)
            for (int r = 0; r < 4; ++r) {
                int m = mt * 16 + g * 4 + r;
                int n = nt * 16 + cl;
                sgn[mt * 8 + nt * 4 + r] = cayley_neg(m, n) ? -1.0f : 1.0f;
            }

    // fixed LDS element offsets (eh from the remapped component kkp)
    const int eh = (kkp >> 4) * 512 + (oo >> 3) * 128 + (kkp & 15) * 8 + (oo & 7);
    const int ex = (lc >> 4) * 512 + (2 + (oc >> 3)) * 128 + (lc & 15) * 8 + (oc & 7);
    const int ea = g * 128 + cl * 8;     // A-frag read base (+512 for mt=1)

    ghi[0][eh] = 0; glo[0][eh] = 0;      // h_0 = 0 (parity-0 h slots)

    float h_reg = 0.0f, xv_prev = 0.0f;
    const float* xrow = x   + (size_t)b * S_ * ND;
    float*       orow = out + (size_t)b * S_ * ND;
    const f32x4 z4 = {0.f, 0.f, 0.f, 0.f};

    // iter s computes h_{s+1} and finishes out[s-1]; iter S_ finishes out[S_-1]
    for (int s = 0; s <= S_; ++s) {
        const int p = s & 1;

        // ---- stage 1: xe (uniform x loads), 4-way ILP, -> G[p] ----
        float xv_cur = 0.0f;
        if (s < S_) {
            const float* xp = xrow + s * ND;
            xv_cur = (tid < ND) ? xp[tid] : 0.0f;
            float xe0 = bin_reg, xe1 = 0.f, xe2 = 0.f, xe3 = 0.f;
            #pragma unroll
            for (int q = 0; q < 28; q += 4) {
                xe0 = fmaf(xp[q + 0], win_reg[q + 0], xe0);
                xe1 = fmaf(xp[q + 1], win_reg[q + 1], xe1);
                xe2 = fmaf(xp[q + 2], win_reg[q + 2], xe2);
                xe3 = fmaf(xp[q + 3], win_reg[q + 3], xe3);
            }
            xe0 = fmaf(xp[28], win_reg[28], xe0);
            xe1 = fmaf(xp[29], win_reg[29], xe1);
            float xe = (xe0 + xe1) + (xe2 + xe3);
            ushort xh, xl; split2(xe, xh, xl);
            ghi[p][ex] = xh; glo[p][ex] = xl;
        }

        // ---- stage 2: out[s-1] partials from h_s (f16 dot2, 2 ILP chains).
        // hf slot index == component -> read order identical; writer half-wave
        // == reader half-wave -> same-wave LDS ordering, no extra barrier. ----
        if (s > 0) {
            const ushort* hp = &hf[p][oc * 32];
            float oa0 = 0.0f, oa1 = 0.0f;
            #pragma unroll
            for (int qq = 0; qq < 2; ++qq) {
                h8 hv0 = *(const h8*)(hp + qq * 8);
                h8 hv1 = *(const h8*)(hp + 16 + qq * 8);
                #pragma unroll
                for (int jj = 0; jj < 4; ++jj) {
                    h2 a0 = {hv0[2 * jj], hv0[2 * jj + 1]};
                    h2 a1 = {hv1[2 * jj], hv1[2 * jj + 1]};
                    oa0 = __builtin_amdgcn_fdot2(a0, wout_h2[qq * 4 + jj], oa0, false);
                    oa1 = __builtin_amdgcn_fdot2(a1, wout_h2[8 + qq * 4 + jj], oa1, false);
                }
            }
            red[p][oc * 32 + lc] = oa0 + oa1;
        }

        BAR();   // the ONE barrier: G[p] (h from s-1 tail, xe), red[p] visible

        // ---- stage 3: finish out[s-1] (global store, never drained) ----
        if (s > 0 && tid < ND) {
            float s0 = 0.f, s1 = 0.f, s2 = 0.f, s3 = 0.f;
            #pragma unroll
            for (int jg = 0; jg < 16; jg += 4) {
                s0 += red[p][(jg + 0) * 32 + tid];
                s1 += red[p][(jg + 1) * 32 + tid];
                s2 += red[p][(jg + 2) * 32 + tid];
                s3 += red[p][(jg + 3) * 32 + tid];
            }
            float ov = xv_prev + bout_reg + ((s0 + s1) + (s2 + s3));
            orow[(size_t)(s - 1) * ND + tid] = ov;
        }

        if (s < S_) {
            // ---- stage 4: A-fragments + 24 MFMA (3-term split, R20-verified) ----
            bf16x8 ah0 = *(const bf16x8*)&ghi[p][ea];
            bf16x8 ah1 = *(const bf16x8*)&ghi[p][ea + 512];
            bf16x8 al0 = *(const bf16x8*)&glo[p][ea];
            bf16x8 al1 = *(const bf16x8*)&glo[p][ea + 512];

            f32x4 acc[2][2][2];      // [o'][mt][nt]
            #pragma unroll
            for (int opi = 0; opi < 2; ++opi) {
                #pragma unroll
                for (int nt = 0; nt < 2; ++nt) {
                    f32x4 t = __builtin_amdgcn_mfma_f32_16x16x32_bf16(ah0, bl[opi][nt], z4, 0, 0, 0);
                    t = __builtin_amdgcn_mfma_f32_16x16x32_bf16(al0, bh[opi][nt], t, 0, 0, 0);
                    acc[opi][0][nt] = __builtin_amdgcn_mfma_f32_16x16x32_bf16(ah0, bh[opi][nt], t, 0, 0, 0);
                    f32x4 u = __builtin_amdgcn_mfma_f32_16x16x32_bf16(ah1, bl[opi][nt], z4, 0, 0, 0);
                    u = __builtin_amdgcn_mfma_f32_16x16x32_bf16(al1, bh[opi][nt], u, 0, 0, 0);
                    acc[opi][1][nt] = __builtin_amdgcn_mfma_f32_16x16x32_bf16(ah1, bh[opi][nt], u, 0, 0, 0);
                }
            }

            // ---- stage 5: sign-fma + in-lane dpp folds -> z0[opi][kt] ----
            float Y[2][2][4];
            #pragma unroll
            for (int opi = 0; opi < 2; ++opi)
                #pragma unroll
                for (int nt = 0; nt < 2; ++nt)
                    #pragma unroll
                    for (int r = 0; r < 4; ++r)
                        Y[opi][nt][r] = fmaf(sgn[nt * 4 + r],
                                             acc[opi][0][nt][r],
                                             sgn[8 + (nt ^ 1) * 4 + r] * acc[opi][1][nt ^ 1][r]);
            float z0[2][2];
            #pragma unroll
            for (int opi = 0; opi < 2; ++opi) {
                #pragma unroll
                for (int kt = 0; kt < 2; ++kt) {
                    float ya0 = Y[opi][kt][0] + dpp_xor1(Y[opi][kt][1]);
                    float ya2 = Y[opi][kt][2] + dpp_xor1(Y[opi][kt][3]);
                    z0[opi][kt] = ya0 + dpp_xor2(ya2);
                }
            }

            // ---- orbit fold, 3 parallel shuffles (R19/R20-verified);
            // F IS this thread's owned component kkp -> no redistribute ----
            float p0 = (g & 2) ? z0[1][0] : z0[0][0];
            float p1 = (g & 2) ? z0[1][1] : z0[0][1];
            float q0 = (g & 2) ? z0[0][0] : z0[1][0];
            float q1 = (g & 2) ? z0[0][1] : z0[1][1];
            float a_ = (g & 1) ? p1 : p0;     // z0[opX][ktX]
            float b_ = (g & 1) ? p0 : p1;     // z0[opX][ktX^1]
            float c_ = (g & 1) ? q1 : q0;     // z0[opX^1][ktX]
            float d_ = (g & 1) ? q0 : q1;     // z0[opX^1][ktX^1]
            float t1 = a_ + __shfl_xor(b_, 20, 64);
            float t2 = __shfl_xor(c_, 40, 64) + __shfl_xor(d_, 60, 64);
            const float delta = t1 + t2;      // = delta[oo][kkp] at this lane

            // ---- stage 6: residual + L2 norm (verified fold order 1,2,4,8,16;
            // lane placement of components permuted -> ulp-scale reassoc only).
            // v_sqrt + v_rcp (~1 ulp each) replace the IEEE div expansion:
            // per-step rel perturbation ~2^-22 -> ~1e-5 final (R12 scaling). ----
            float hc = h_reg + delta;
            float ss = hc * hc;
            ss += dpp_xor1(ss);
            ss += dpp_xor2(ss);
            ss += __shfl_xor(ss, 4, 32);
            ss += __shfl_xor(ss, 8, 32);
            ss += __shfl_xor(ss, 16, 32);
            h_reg = hc * __builtin_amdgcn_rcpf(__builtin_amdgcn_sqrtf(ss) + EPS_);

            // ---- stage 7: h_{s+1} -> parity p^1 ----
            ushort hh, hl; split2(h_reg, hh, hl);
            ghi[p ^ 1][eh] = hh; glo[p ^ 1][eh] = hl;
            hf[p ^ 1][oo * 32 + kkp] = f2h(h_reg);   // slot == component
        }

        xv_prev = xv_cur;
    }
}

extern "C" void kernel_launch(void* const* d_in, const int* in_sizes, int n_in,
                              void* d_out, int out_size, void* d_ws, size_t ws_size,
                              hipStream_t stream) {
    const float* x     = (const float*)d_in[0];
    const float* W_in  = (const float*)d_in[1];
    const float* b_in  = (const float*)d_in[2];
    const float* w_h   = (const float*)d_in[3];
    const float* w_x   = (const float*)d_in[4];
    const float* W_out = (const float*)d_in[5];
    const float* b_out = (const float*)d_in[6];
    float* outp = (float*)d_out;

    versor_kernel<<<256, 512, 0, stream>>>(x, W_in, b_in, w_h, w_x, W_out, b_out, outp);
}